// Round 8
// baseline (1172.730 us; speedup 1.0000x reference)
//
#include <hip/hip_runtime.h>
#include <math.h>

#define H 200
#define NBLK 512
constexpr float INV_PI = 0.31830988618379067f;

typedef __attribute__((ext_vector_type(8))) short bf16x8;
typedef __attribute__((ext_vector_type(4))) float f32x4;
typedef __attribute__((ext_vector_type(4))) short s16x4;

__device__ __forceinline__ short f2bf(float f) {
  unsigned u = __float_as_uint(f);
  u += 0x7FFF + ((u >> 16) & 1);  // RNE
  return (short)(u >> 16);
}
__device__ __forceinline__ float bf2f(short s) {
  return __uint_as_float(((unsigned)(unsigned short)s) << 16);
}
__device__ __forceinline__ float angsim(float c) {
  c = fminf(fmaxf(c * 0.99999f, -1.f), 1.f);
  return 1.f - acosf(c) * INV_PI;
}
__device__ __forceinline__ const float* sel_mod(int m, const float* xa, const float* xv,
                                                const float* xt) {
  return (m == 0) ? xa : ((m == 1) ? xv : xt);
}

// ---- device-scope grid barrier (generation counter; cross-XCD safe) ----
__device__ __forceinline__ void grid_barrier(unsigned* cnt, unsigned* gen) {
  __syncthreads();
  __threadfence();  // release: my block's writes visible device-wide
  if (threadIdx.x == 0) {
    unsigned g = __hip_atomic_load(gen, __ATOMIC_RELAXED, __HIP_MEMORY_SCOPE_AGENT);
    unsigned arrived =
        __hip_atomic_fetch_add(cnt, 1u, __ATOMIC_ACQ_REL, __HIP_MEMORY_SCOPE_AGENT);
    if (arrived == NBLK - 1) {
      __hip_atomic_store(cnt, 0u, __ATOMIC_RELAXED, __HIP_MEMORY_SCOPE_AGENT);
      __hip_atomic_store(gen, g + 1u, __ATOMIC_RELEASE, __HIP_MEMORY_SCOPE_AGENT);
    } else {
      while (__hip_atomic_load(gen, __ATOMIC_ACQUIRE, __HIP_MEMORY_SCOPE_AGENT) == g)
        __builtin_amdgcn_s_sleep(1);
    }
  }
  __syncthreads();
  __threadfence();  // acquire: see other blocks' writes
}

// ---- 16x16 per-wave MFMA core: direct global, K = NK*32 ----
template <int NK>
__device__ __forceinline__ void gemm1(const short* __restrict__ A, int lda,
                                      const short* __restrict__ B, int ldb, f32x4& acc) {
  const int l = threadIdx.x & 63;
  const short* ap = A + (l & 15) * lda + (l >> 4) * 8;
  const short* bp = B + (l & 15) * ldb + (l >> 4) * 8;
  #pragma unroll
  for (int t = 0; t < NK; t++) {
    bf16x8 a = *(const bf16x8*)(ap + t * 32);
    bf16x8 b = *(const bf16x8*)(bp + t * 32);
    acc = __builtin_amdgcn_mfma_f32_16x16x32_bf16(a, b, acc, 0, 0, 0);
  }
}

// ---- 16x64 per-wave core (intra Gram) ----
template <int NK>
__device__ __forceinline__ void gemm4(const short* __restrict__ A, int lda,
                                      const short* __restrict__ B, int ldb, f32x4 acc[4]) {
  const int l = threadIdx.x & 63;
  const short* ap = A + (l & 15) * lda + (l >> 4) * 8;
  const short* bp = B + (l & 15) * ldb + (l >> 4) * 8;
  const int o16 = 16 * ldb, o32 = 32 * ldb, o48 = 48 * ldb;
  #pragma unroll
  for (int t = 0; t < NK; t++) {
    bf16x8 a = *(const bf16x8*)(ap + t * 32);
    bf16x8 b0 = *(const bf16x8*)(bp + t * 32);
    bf16x8 b1 = *(const bf16x8*)(bp + o16 + t * 32);
    bf16x8 b2 = *(const bf16x8*)(bp + o32 + t * 32);
    bf16x8 b3 = *(const bf16x8*)(bp + o48 + t * 32);
    acc[0] = __builtin_amdgcn_mfma_f32_16x16x32_bf16(a, b0, acc[0], 0, 0, 0);
    acc[1] = __builtin_amdgcn_mfma_f32_16x16x32_bf16(a, b1, acc[1], 0, 0, 0);
    acc[2] = __builtin_amdgcn_mfma_f32_16x16x32_bf16(a, b2, acc[2], 0, 0, 0);
    acc[3] = __builtin_amdgcn_mfma_f32_16x16x32_bf16(a, b3, acc[3], 0, 0, 0);
  }
}

__global__ __launch_bounds__(256, 2) void mono_k(
    const float* __restrict__ xa, const float* __restrict__ xv, const float* __restrict__ xt,
    const float* __restrict__ fc0_w, const float* __restrict__ fc0_b,
    const float* __restrict__ conv_w, const float* __restrict__ tm_w,
    const float* __restrict__ tm_b, const float* __restrict__ cross_w,
    const float* __restrict__ cross_b, const float* __restrict__ uniw,
    const float* __restrict__ unib,
    short* __restrict__ fc0_wt, short* __restrict__ conv_wt, short* __restrict__ tm_wt,
    short* __restrict__ cross_wt, short* __restrict__ bigA, short* __restrict__ tmA,
    short* __restrict__ convA, short* __restrict__ hxb, short* __restrict__ h_t,
    short* __restrict__ intra_s, float* __restrict__ inv_norm, float* __restrict__ cw,
    float* __restrict__ dinv, unsigned* __restrict__ syncv, float* __restrict__ out) {
  __shared__ float tile[64][65];
  __shared__ float sdinv[64];
  const int bx = blockIdx.x;
  const int lane = threadIdx.x & 63;
  const int w = threadIdx.x >> 6;
  const int wave = bx * 4 + w;
  unsigned* cnt = syncv;
  unsigned* gen = syncv + 1;
  const int jm_t[6] = {1, 2, 0, 2, 0, 1};

  // ================= S1: weight transpose + pack x + norms + sims + zero out ==========
  for (int t = bx; t < 444; t += NBLK) {
    const float* src; short* dst; int srcK, KP, kt, ct;
    if (t < 16) {
      src = fc0_w; dst = fc0_wt; srcK = 200; KP = 224; kt = t >> 2; ct = t & 3;
    } else if (t < 156) {
      int b = (t - 16) / 28, rem = (t - 16) % 28;
      kt = rem >> 2; ct = rem & 3; srcK = 400; KP = 416;
      if (b < 2) { src = conv_w + b * 80000; dst = conv_wt + b * 86528; }
      else { src = tm_w + (b - 2) * 80000; dst = tm_wt + (b - 2) * 86528; }
    } else {
      int q = t - 156, pp = q >> 4, rem = q & 15;
      kt = rem >> 2; ct = rem & 3; srcK = 200; KP = 224;
      src = cross_w + (pp / 3) * 120000 + (pp % 3) * 40000;
      dst = cross_wt + pp * (208 * 224);
    }
    const int k0 = kt * 64, c0 = ct * 64;
    #pragma unroll 4
    for (int r = 0; r < 16; r++) {
      int ky = r * 4 + w, k = k0 + ky, c = c0 + lane;
      tile[ky][lane] = (k < srcK && c < 200) ? src[k * 200 + c] : 0.f;
    }
    __syncthreads();
    #pragma unroll 4
    for (int r = 0; r < 16; r++) {
      int cy = r * 4 + w, c = c0 + cy, k = k0 + lane;
      if (c < 208 && k < KP) dst[c * KP + k] = f2bf(tile[lane][cy]);
    }
    __syncthreads();
  }
  for (int u = wave; u < 6144; u += NBLK * 4) {
    int m = u >> 11, a = u & 2047;
    const float* p = sel_mod(m, xa, xv, xt) + a * H;
    float v0 = p[lane], v1 = p[lane + 64], v2 = p[lane + 128];
    float v3 = (lane < 8) ? p[lane + 192] : 0.f;
    float s = v0 * v0 + v1 * v1 + v2 * v2 + v3 * v3;
    #pragma unroll
    for (int off = 32; off; off >>= 1) s += __shfl_down(s, off, 64);
    if (lane == 0) inv_norm[u] = 1.f / sqrtf(s);
    short b0 = f2bf(v0), b1 = f2bf(v1), b2 = f2bf(v2), b3 = f2bf(v3);
    short* br = bigA + u * 224;
    br[lane] = b0; br[lane + 64] = b1; br[lane + 128] = b2;
    if (lane < 32) br[192 + lane] = (lane < 8) ? b3 : (short)0;
    short* tr = tmA + u * 416;
    tr[lane] = b0; tr[lane + 64] = b1; tr[lane + 128] = b2;
    if (lane < 8) tr[192 + lane] = b3;
    if (lane < 16) { tr[400 + lane] = 0; convA[u * 416 + 400 + lane] = 0; }
    if (lane < 24) hxb[u * 224 + 200 + lane] = 0;
  }
  for (int a = wave; a < 2048; a += NBLK * 4) {
    const float* pa = xa + a * H;
    const float* pv = xv + a * H;
    const float* pt = xt + a * H;
    float a0 = pa[lane], a1 = pa[lane + 64], a2 = pa[lane + 128],
          a3 = (lane < 8) ? pa[lane + 192] : 0.f;
    float q0 = pv[lane], q1 = pv[lane + 64], q2 = pv[lane + 128],
          q3 = (lane < 8) ? pv[lane + 192] : 0.f;
    float t0 = pt[lane], t1 = pt[lane + 64], t2 = pt[lane + 128],
          t3 = (lane < 8) ? pt[lane + 192] : 0.f;
    float red[6];
    red[0] = a0 * a0 + a1 * a1 + a2 * a2 + a3 * a3;
    red[1] = q0 * q0 + q1 * q1 + q2 * q2 + q3 * q3;
    red[2] = t0 * t0 + t1 * t1 + t2 * t2 + t3 * t3;
    red[3] = a0 * q0 + a1 * q1 + a2 * q2 + a3 * q3;
    red[4] = a0 * t0 + a1 * t1 + a2 * t2 + a3 * t3;
    red[5] = q0 * t0 + q1 * t1 + q2 * t2 + q3 * t3;
    #pragma unroll
    for (int off = 32; off; off >>= 1)
      #pragma unroll
      for (int q = 0; q < 6; q++) red[q] += __shfl_down(red[q], off, 64);
    if (lane == 0) {
      float ia = 1.f / sqrtf(red[0]), iv = 1.f / sqrtf(red[1]), it = 1.f / sqrtf(red[2]);
      cw[a] = angsim(red[3] * ia * iv);
      cw[2048 + a] = angsim(red[4] * ia * it);
      cw[4096 + a] = angsim(red[5] * iv * it);
    }
  }
  {
    int g = bx * 256 + threadIdx.x;
    if (g < 3072) *(f32x4*)(out + g * 4) = f32x4{0.f, 0.f, 0.f, 0.f};
  }
  grid_barrier(cnt, gen);

  // ================= S2: intra Gram (+dinv, dinv-folded output) || fc0 =================
  for (int t = bx; t < 1344; t += NBLK) {
    if (t < 96) {
      const int mb = t;
      f32x4 acc[4] = {};
      gemm4<7>(bigA + (mb * 64 + w * 16) * 224, 224, bigA + mb * 64 * 224, 224, acc);
      const int fr = lane & 15, fq = lane >> 4;
      const int iL0 = w * 16 + fq * 4, u0 = mb * 64;
      float ang[4][4];
      float rsum[4] = {0.f, 0.f, 0.f, 0.f};
      #pragma unroll
      for (int j = 0; j < 4; j++) {
        float invj = inv_norm[u0 + j * 16 + fr];
        #pragma unroll
        for (int r = 0; r < 4; r++) {
          float av = angsim(acc[j][r] * inv_norm[u0 + iL0 + r] * invj);
          ang[j][r] = av;
          rsum[r] += av;
        }
      }
      #pragma unroll
      for (int mask = 1; mask < 16; mask <<= 1)
        #pragma unroll
        for (int r = 0; r < 4; r++) rsum[r] += __shfl_xor(rsum[r], mask, 64);
      if (fr == 0) {
        int m = u0 >> 11;
        #pragma unroll
        for (int r = 0; r < 4; r++) {
          int u = u0 + iL0 + r, a = u & 2047;
          float c1 = (m <= 1) ? cw[a] : cw[2048 + a];
          float c2 = (m == 0) ? cw[2048 + a] : cw[4096 + a];
          float dv = 1.f / sqrtf(rsum[r] + c1 + c2);
          dinv[u] = dv;
          sdinv[iL0 + r] = dv;
        }
      }
      __syncthreads();
      #pragma unroll
      for (int j = 0; j < 4; j++) {
        int jn = j * 16 + fr;
        float dj = sdinv[jn];
        #pragma unroll
        for (int r = 0; r < 4; r++)
          intra_s[mb * 4096 + (iL0 + r) * 64 + jn] = f2bf(ang[j][r] * sdinv[iL0 + r] * dj);
      }
      __syncthreads();
    } else {
      const int q = t - 96;
      const int c0 = (q / 96) * 16;
      const int n0 = ((q % 96) * 4 + w) * 16;
      f32x4 acc = {};
      gemm1<7>(fc0_wt + c0 * 224, 224, bigA + n0 * 224, 224, acc);
      const int node = n0 + (lane & 15), cb = c0 + (lane >> 4) * 4;
      if (cb < 200) {
        s16x4 oh;
        #pragma unroll
        for (int r = 0; r < 4; r++) {
          float v = fmaxf(acc[r] + fc0_b[cb + r], 0.f);
          oh[r] = f2bf(v);
          h_t[(cb + r) * 6144 + node] = oh[r];
        }
        *(s16x4*)(convA + node * 416 + 200 + cb) = oh;
      }
    }
  }
  grid_barrier(cnt, gen);

  // ================= GCNII layers: adj -> conv, twice =================
  #pragma unroll 1
  for (int layer = 0; layer < 2; layer++) {
    for (int t = bx; t < 1248; t += NBLK) {  // adj
      const int ct = t / 96, mb = t - ct * 96;
      const int c0 = ct * 16, nbase = mb * 64;
      f32x4 acc = {};
      gemm1<2>(h_t + c0 * 6144 + nbase, 6144, intra_s + mb * 4096 + w * 16 * 64, 64, acc);
      const int u = nbase + w * 16 + (lane & 15), cb = c0 + (lane >> 4) * 4;
      if (cb < 200) {
        const int m = u >> 11, a = u & 2047;
        int n1, n2, p1, p2;
        if (m == 0)      { n1 = 1; p1 = 0; n2 = 2; p2 = 1; }
        else if (m == 1) { n1 = 0; p1 = 0; n2 = 2; p2 = 2; }
        else             { n1 = 0; p1 = 1; n2 = 1; p2 = 2; }
        float dv = dinv[u];
        int o1 = n1 * 2048 + a, o2 = n2 * 2048 + a;
        float w1 = cw[p1 * 2048 + a] * dv * dinv[o1];
        float w2 = cw[p2 * 2048 + a] * dv * dinv[o2];
        s16x4 o;
        #pragma unroll
        for (int r = 0; r < 4; r++) {
          int c = cb + r;
          float v = acc[r] + w1 * bf2f(h_t[c * 6144 + o1]) + w2 * bf2f(h_t[c * 6144 + o2]);
          o[r] = f2bf(v);
        }
        *(s16x4*)(convA + u * 416 + cb) = o;
      }
    }
    grid_barrier(cnt, gen);

    const float beta = (layer == 0) ? 0.40546510810816444f : 0.22314355131420976f;
    const float ombeta = 1.f - beta;
    const short* Wt = conv_wt + layer * 86528;
    for (int t = bx; t < 1248; t += NBLK) {  // conv
      const int c0 = (t / 96) * 16;
      const int n0 = ((t % 96) * 4 + w) * 16;
      f32x4 acc = {};
      gemm1<13>(Wt + c0 * 416, 416, convA + n0 * 416, 416, acc);
      const int node = n0 + (lane & 15), cb = c0 + (lane >> 4) * 4;
      if (cb < 200) {
        s16x4 hiv = *(const s16x4*)(convA + node * 416 + cb);
        s16x4 h0v = *(const s16x4*)(convA + node * 416 + 200 + cb);
        if (layer == 0) {
          #pragma unroll
          for (int r = 0; r < 4; r++) {
            float rr = 0.9f * bf2f(hiv[r]) + 0.1f * bf2f(h0v[r]);
            float v = fmaxf(beta * acc[r] + ombeta * rr, 0.f);
            h_t[(cb + r) * 6144 + node] = f2bf(v);
          }
        } else {
          s16x4 o;
          #pragma unroll
          for (int r = 0; r < 4; r++) {
            float rr = 0.9f * bf2f(hiv[r]) + 0.1f * bf2f(h0v[r]);
            float v = fmaxf(beta * acc[r] + ombeta * rr, 0.f);
            o[r] = f2bf(v);
          }
          *(s16x4*)(tmA + node * 416 + 200 + cb) = o;
        }
      }
    }
    grid_barrier(cnt, gen);
  }

  // ================= S7: tm =================
  for (int t = bx; t < 1248; t += NBLK) {
    const int m = t / 416, rem = t - m * 416;
    const int c0 = (rem / 32) * 16;
    const int n0 = ((rem % 32) * 4 + w) * 16;
    f32x4 acc = {};
    gemm1<13>(tm_wt + m * 86528 + c0 * 416, 416, tmA + (m * 2048 + n0) * 416, 416, acc);
    const int node = n0 + (lane & 15), cb = c0 + (lane >> 4) * 4;
    if (cb < 200) {
      s16x4 o;
      #pragma unroll
      for (int r = 0; r < 4; r++) o[r] = f2bf(fmaxf(acc[r] + tm_b[m * H + cb + r], 0.f));
      *(s16x4*)(hxb + (m * 2048 + node) * 224 + cb) = o;
    }
  }
  grid_barrier(cnt, gen);

  // ================= S8: cross gate (3-phase) + fused final projection =================
  for (int t = bx; t < 2496; t += NBLK) {
    const int p = t / 416, rem = t - p * 416;
    const int cj = rem / 32;
    const int c0 = cj * 16;
    const int n0 = ((rem % 32) * 4 + w) * 16;
    const int im = p >> 1, jm = jm_t[p];
    const short* Wp = cross_wt + p * (3 * 208 * 224);
    const short* Bi = hxb + (im * 2048 + n0) * 224;
    const short* Bj = hxb + (jm * 2048 + n0) * 224;
    f32x4 acc = {};
    gemm1<7>(Wp + c0 * 224, 224, Bi, 224, acc);
    gemm1<7>(Wp + 208 * 224 + c0 * 224, 224, Bj, 224, acc);
    {
      const short* ap = Wp + 2 * 208 * 224 + (c0 + (lane & 15)) * 224 + (lane >> 4) * 8;
      const short* bpi = Bi + (lane & 15) * 224 + (lane >> 4) * 8;
      const short* bpj = Bj + (lane & 15) * 224 + (lane >> 4) * 8;
      #pragma unroll
      for (int tt = 0; tt < 7; tt++) {
        bf16x8 a = *(const bf16x8*)(ap + tt * 32);
        bf16x8 bi = *(const bf16x8*)(bpi + tt * 32);
        bf16x8 bj = *(const bf16x8*)(bpj + tt * 32);
        bf16x8 pr;
        #pragma unroll
        for (int e = 0; e < 8; e++) pr[e] = f2bf(bf2f(bi[e]) * bf2f(bj[e]));
        acc = __builtin_amdgcn_mfma_f32_16x16x32_bf16(a, pr, acc, 0, 0, 0);
      }
    }
    const int node = n0 + (lane & 15), cb = c0 + (lane >> 4) * 4;
    float pt[6] = {0.f, 0.f, 0.f, 0.f, 0.f, 0.f};
    if (cb < 200) {
      s16x4 ai = *(const s16x4*)(hxb + (im * 2048 + node) * 224 + cb);
      s16x4 aj = *(const s16x4*)(hxb + (jm * 2048 + node) * 224 + cb);
      const float* Wu = uniw + im * (H * 6);
      #pragma unroll
      for (int r = 0; r < 4; r++) {
        float x = acc[r] + cross_b[p * H + cb + r];
        float z = 1.f / (1.f + expf(-x));
        float o = z * bf2f(ai[r]) + (1.f - z) * bf2f(aj[r]);
        #pragma unroll
        for (int tt = 0; tt < 6; tt++) pt[tt] += o * Wu[(cb + r) * 6 + tt];
      }
    }
    #pragma unroll
    for (int tt = 0; tt < 6; tt++) {
      pt[tt] += __shfl_xor(pt[tt], 16, 64);
      pt[tt] += __shfl_xor(pt[tt], 32, 64);
    }
    if ((lane >> 4) == 0) {
      if (p == 0 && cj == 0) {
        #pragma unroll
        for (int tt = 0; tt < 6; tt++) pt[tt] += unib[tt] + unib[6 + tt] + unib[12 + tt];
      }
      #pragma unroll
      for (int tt = 0; tt < 6; tt++) atomicAdd(out + node * 6 + tt, pt[tt]);
    }
  }
}

extern "C" void kernel_launch(void* const* d_in, const int* in_sizes, int n_in,
                              void* d_out, int out_size, void* d_ws, size_t ws_size,
                              hipStream_t stream) {
  const float* xa = (const float*)d_in[0];
  const float* xv = (const float*)d_in[1];
  const float* xt = (const float*)d_in[2];
  const float* fc0_w = (const float*)d_in[3];
  const float* fc0_b = (const float*)d_in[4];
  const float* conv_w = (const float*)d_in[5];
  const float* tm_w = (const float*)d_in[6];
  const float* tm_b = (const float*)d_in[7];
  const float* cross_w = (const float*)d_in[8];
  const float* cross_b = (const float*)d_in[9];
  const float* uni_w = (const float*)d_in[10];
  const float* uni_b = (const float*)d_in[11];
  float* out = (float*)d_out;
  float* ws = (float*)d_ws;

  float* inv_norm = ws;                       // 6144
  float* dinv = ws + 6144;                    // 6144
  float* cw = ws + 12288;                     // 6144
  short* bigA = (short*)(ws + 18432);         // 6144*224 sh -> 706560
  short* convA = (short*)(ws + 706560);       // 6144*416 sh -> 1984512
  short* tmA = (short*)(ws + 1984512);        // 6144*416 sh -> 3262464
  short* hxb = (short*)(ws + 3262464);        // 6144*224 sh -> 3950592
  short* h_t = (short*)(ws + 3950592);        // 208*6144 sh -> 4589568
  short* intra_s = (short*)(ws + 4589568);    // 96*4096 sh -> 4786176
  short* fc0_wt = (short*)(ws + 4786176);     // 208*224 sh -> 4809472
  short* conv_wt = (short*)(ws + 4809472);    // 2*208*416 sh -> 4896000
  short* tm_wt = (short*)(ws + 4896000);      // 3*208*416 sh -> 5025792
  short* cross_wt = (short*)(ws + 5025792);   // 18*208*224 sh -> 5445120
  unsigned* syncv = (unsigned*)(ws + 5445120);

  hipMemsetAsync(syncv, 0, 16, stream);
  mono_k<<<NBLK, 256, 0, stream>>>(xa, xv, xt, fc0_w, fc0_b, conv_w, tm_w, tm_b,
                                   cross_w, cross_b, uni_w, uni_b,
                                   fc0_wt, conv_wt, tm_wt, cross_wt, bigA, tmA, convA,
                                   hxb, h_t, intra_s, inv_norm, cw, dinv, syncv, out);
}

// Round 9
// 297.543 us; speedup vs baseline: 3.9414x; 3.9414x over previous
//
#include <hip/hip_runtime.h>
#include <math.h>

#define H 200
#define NBLK 512
constexpr float INV_PI = 0.31830988618379067f;

typedef __attribute__((ext_vector_type(8))) short bf16x8;
typedef __attribute__((ext_vector_type(4))) float f32x4;
typedef __attribute__((ext_vector_type(4))) short s16x4;

__device__ __forceinline__ short f2bf(float f) {
  unsigned u = __float_as_uint(f);
  u += 0x7FFF + ((u >> 16) & 1);  // RNE
  return (short)(u >> 16);
}
__device__ __forceinline__ float bf2f(short s) {
  return __uint_as_float(((unsigned)(unsigned short)s) << 16);
}
__device__ __forceinline__ float angsim(float c) {
  c = fminf(fmaxf(c * 0.99999f, -1.f), 1.f);
  return 1.f - acosf(c) * INV_PI;
}
__device__ __forceinline__ const float* sel_mod(int m, const float* xa, const float* xv,
                                                const float* xt) {
  return (m == 0) ? xa : ((m == 1) ? xv : xt);
}

// ---- device-scope grid barrier: relaxed polling, one acquire fence, no RMW hotspot ----
// slots: NBLK padded words (stride 4 uints). gen: 1 word. All zeroed before launch.
__device__ __forceinline__ void grid_barrier(unsigned* __restrict__ slots,
                                             unsigned* __restrict__ gen, unsigned g) {
  __syncthreads();
  if (threadIdx.x == 0)  // release: flushes this block's dirty L2 once, announces arrival
    __hip_atomic_store(slots + (unsigned)blockIdx.x * 4u, g, __ATOMIC_RELEASE,
                       __HIP_MEMORY_SCOPE_AGENT);
  if (blockIdx.x == 0) {
    // detector: 256 threads watch 2 slots each, RELAXED (no cache invalidates)
    while (__hip_atomic_load(slots + threadIdx.x * 4u, __ATOMIC_RELAXED,
                             __HIP_MEMORY_SCOPE_AGENT) < g)
      __builtin_amdgcn_s_sleep(1);
    while (__hip_atomic_load(slots + (threadIdx.x + 256u) * 4u, __ATOMIC_RELAXED,
                             __HIP_MEMORY_SCOPE_AGENT) < g)
      __builtin_amdgcn_s_sleep(1);
    __syncthreads();
    if (threadIdx.x == 0)
      __hip_atomic_store(gen, g, __ATOMIC_RELEASE, __HIP_MEMORY_SCOPE_AGENT);
  } else if (threadIdx.x == 0) {
    while (__hip_atomic_load(gen, __ATOMIC_RELAXED, __HIP_MEMORY_SCOPE_AGENT) < g)
      __builtin_amdgcn_s_sleep(1);
  }
  __syncthreads();
  if (threadIdx.x < 64) __builtin_amdgcn_fence(__ATOMIC_ACQUIRE, "agent");  // one inv/block
  __syncthreads();
}

// ---- 16x16 per-wave MFMA core: direct global, K = NK*32 ----
template <int NK>
__device__ __forceinline__ void gemm1(const short* __restrict__ A, int lda,
                                      const short* __restrict__ B, int ldb, f32x4& acc) {
  const int l = threadIdx.x & 63;
  const short* ap = A + (l & 15) * lda + (l >> 4) * 8;
  const short* bp = B + (l & 15) * ldb + (l >> 4) * 8;
  #pragma unroll
  for (int t = 0; t < NK; t++) {
    bf16x8 a = *(const bf16x8*)(ap + t * 32);
    bf16x8 b = *(const bf16x8*)(bp + t * 32);
    acc = __builtin_amdgcn_mfma_f32_16x16x32_bf16(a, b, acc, 0, 0, 0);
  }
}

// ---- 16x64 per-wave core (intra Gram) ----
template <int NK>
__device__ __forceinline__ void gemm4(const short* __restrict__ A, int lda,
                                      const short* __restrict__ B, int ldb, f32x4 acc[4]) {
  const int l = threadIdx.x & 63;
  const short* ap = A + (l & 15) * lda + (l >> 4) * 8;
  const short* bp = B + (l & 15) * ldb + (l >> 4) * 8;
  const int o16 = 16 * ldb, o32 = 32 * ldb, o48 = 48 * ldb;
  #pragma unroll
  for (int t = 0; t < NK; t++) {
    bf16x8 a = *(const bf16x8*)(ap + t * 32);
    bf16x8 b0 = *(const bf16x8*)(bp + t * 32);
    bf16x8 b1 = *(const bf16x8*)(bp + o16 + t * 32);
    bf16x8 b2 = *(const bf16x8*)(bp + o32 + t * 32);
    bf16x8 b3 = *(const bf16x8*)(bp + o48 + t * 32);
    acc[0] = __builtin_amdgcn_mfma_f32_16x16x32_bf16(a, b0, acc[0], 0, 0, 0);
    acc[1] = __builtin_amdgcn_mfma_f32_16x16x32_bf16(a, b1, acc[1], 0, 0, 0);
    acc[2] = __builtin_amdgcn_mfma_f32_16x16x32_bf16(a, b2, acc[2], 0, 0, 0);
    acc[3] = __builtin_amdgcn_mfma_f32_16x16x32_bf16(a, b3, acc[3], 0, 0, 0);
  }
}

__global__ __launch_bounds__(256, 2) void mono_k(
    const float* __restrict__ xa, const float* __restrict__ xv, const float* __restrict__ xt,
    const float* __restrict__ fc0_w, const float* __restrict__ fc0_b,
    const float* __restrict__ conv_w, const float* __restrict__ tm_w,
    const float* __restrict__ tm_b, const float* __restrict__ cross_w,
    const float* __restrict__ cross_b, const float* __restrict__ uniw,
    const float* __restrict__ unib,
    short* __restrict__ fc0_wt, short* __restrict__ conv_wt, short* __restrict__ tm_wt,
    short* __restrict__ cross_wt, short* __restrict__ bigA, short* __restrict__ tmA,
    short* __restrict__ convA, short* __restrict__ hxb, short* __restrict__ h_t,
    short* __restrict__ intra_s, float* __restrict__ inv_norm, float* __restrict__ cw,
    float* __restrict__ dinv, unsigned* __restrict__ syncv, float* __restrict__ out) {
  __shared__ float tile[64][65];
  __shared__ float sdinv[64];
  const int bx = blockIdx.x;
  const int lane = threadIdx.x & 63;
  const int w = threadIdx.x >> 6;
  const int wave = bx * 4 + w;
  unsigned* gen = syncv;
  unsigned* slots = syncv + 64;
  unsigned gctr = 0;
  const int jm_t[6] = {1, 2, 0, 2, 0, 1};

  // ================= S1: weight transpose + pack x + norms + sims + zero out ==========
  for (int t = bx; t < 444; t += NBLK) {
    const float* src; short* dst; int srcK, KP, kt, ct;
    if (t < 16) {
      src = fc0_w; dst = fc0_wt; srcK = 200; KP = 224; kt = t >> 2; ct = t & 3;
    } else if (t < 156) {
      int b = (t - 16) / 28, rem = (t - 16) % 28;
      kt = rem >> 2; ct = rem & 3; srcK = 400; KP = 416;
      if (b < 2) { src = conv_w + b * 80000; dst = conv_wt + b * 86528; }
      else { src = tm_w + (b - 2) * 80000; dst = tm_wt + (b - 2) * 86528; }
    } else {
      int q = t - 156, pp = q >> 4, rem = q & 15;
      kt = rem >> 2; ct = rem & 3; srcK = 200; KP = 224;
      src = cross_w + (pp / 3) * 120000 + (pp % 3) * 40000;
      dst = cross_wt + pp * (208 * 224);
    }
    const int k0 = kt * 64, c0 = ct * 64;
    #pragma unroll 4
    for (int r = 0; r < 16; r++) {
      int ky = r * 4 + w, k = k0 + ky, c = c0 + lane;
      tile[ky][lane] = (k < srcK && c < 200) ? src[k * 200 + c] : 0.f;
    }
    __syncthreads();
    #pragma unroll 4
    for (int r = 0; r < 16; r++) {
      int cy = r * 4 + w, c = c0 + cy, k = k0 + lane;
      if (c < 208 && k < KP) dst[c * KP + k] = f2bf(tile[lane][cy]);
    }
    __syncthreads();
  }
  for (int u = wave; u < 6144; u += NBLK * 4) {
    int m = u >> 11, a = u & 2047;
    const float* p = sel_mod(m, xa, xv, xt) + a * H;
    float v0 = p[lane], v1 = p[lane + 64], v2 = p[lane + 128];
    float v3 = (lane < 8) ? p[lane + 192] : 0.f;
    float s = v0 * v0 + v1 * v1 + v2 * v2 + v3 * v3;
    #pragma unroll
    for (int off = 32; off; off >>= 1) s += __shfl_down(s, off, 64);
    if (lane == 0) inv_norm[u] = 1.f / sqrtf(s);
    short b0 = f2bf(v0), b1 = f2bf(v1), b2 = f2bf(v2), b3 = f2bf(v3);
    short* br = bigA + u * 224;
    br[lane] = b0; br[lane + 64] = b1; br[lane + 128] = b2;
    if (lane < 32) br[192 + lane] = (lane < 8) ? b3 : (short)0;
    short* tr = tmA + u * 416;
    tr[lane] = b0; tr[lane + 64] = b1; tr[lane + 128] = b2;
    if (lane < 8) tr[192 + lane] = b3;
    if (lane < 16) { tr[400 + lane] = 0; convA[u * 416 + 400 + lane] = 0; }
    if (lane < 24) hxb[u * 224 + 200 + lane] = 0;
  }
  for (int a = wave; a < 2048; a += NBLK * 4) {
    const float* pa = xa + a * H;
    const float* pv = xv + a * H;
    const float* pt = xt + a * H;
    float a0 = pa[lane], a1 = pa[lane + 64], a2 = pa[lane + 128],
          a3 = (lane < 8) ? pa[lane + 192] : 0.f;
    float q0 = pv[lane], q1 = pv[lane + 64], q2 = pv[lane + 128],
          q3 = (lane < 8) ? pv[lane + 192] : 0.f;
    float t0 = pt[lane], t1 = pt[lane + 64], t2 = pt[lane + 128],
          t3 = (lane < 8) ? pt[lane + 192] : 0.f;
    float red[6];
    red[0] = a0 * a0 + a1 * a1 + a2 * a2 + a3 * a3;
    red[1] = q0 * q0 + q1 * q1 + q2 * q2 + q3 * q3;
    red[2] = t0 * t0 + t1 * t1 + t2 * t2 + t3 * t3;
    red[3] = a0 * q0 + a1 * q1 + a2 * q2 + a3 * q3;
    red[4] = a0 * t0 + a1 * t1 + a2 * t2 + a3 * t3;
    red[5] = q0 * t0 + q1 * t1 + q2 * t2 + q3 * t3;
    #pragma unroll
    for (int off = 32; off; off >>= 1)
      #pragma unroll
      for (int q = 0; q < 6; q++) red[q] += __shfl_down(red[q], off, 64);
    if (lane == 0) {
      float ia = 1.f / sqrtf(red[0]), iv = 1.f / sqrtf(red[1]), it = 1.f / sqrtf(red[2]);
      cw[a] = angsim(red[3] * ia * iv);
      cw[2048 + a] = angsim(red[4] * ia * it);
      cw[4096 + a] = angsim(red[5] * iv * it);
    }
  }
  {
    int g = bx * 256 + threadIdx.x;
    if (g < 3072) *(f32x4*)(out + g * 4) = f32x4{0.f, 0.f, 0.f, 0.f};
  }
  grid_barrier(slots, gen, ++gctr);

  // ================= S2: intra Gram (+dinv, dinv-folded output) || fc0 =================
  for (int t = bx; t < 1344; t += NBLK) {
    if (t < 96) {
      const int mb = t;
      f32x4 acc[4] = {};
      gemm4<7>(bigA + (mb * 64 + w * 16) * 224, 224, bigA + mb * 64 * 224, 224, acc);
      const int fr = lane & 15, fq = lane >> 4;
      const int iL0 = w * 16 + fq * 4, u0 = mb * 64;
      float ang[4][4];
      float rsum[4] = {0.f, 0.f, 0.f, 0.f};
      #pragma unroll
      for (int j = 0; j < 4; j++) {
        float invj = inv_norm[u0 + j * 16 + fr];
        #pragma unroll
        for (int r = 0; r < 4; r++) {
          float av = angsim(acc[j][r] * inv_norm[u0 + iL0 + r] * invj);
          ang[j][r] = av;
          rsum[r] += av;
        }
      }
      #pragma unroll
      for (int mask = 1; mask < 16; mask <<= 1)
        #pragma unroll
        for (int r = 0; r < 4; r++) rsum[r] += __shfl_xor(rsum[r], mask, 64);
      if (fr == 0) {
        int m = u0 >> 11;
        #pragma unroll
        for (int r = 0; r < 4; r++) {
          int u = u0 + iL0 + r, a = u & 2047;
          float c1 = (m <= 1) ? cw[a] : cw[2048 + a];
          float c2 = (m == 0) ? cw[2048 + a] : cw[4096 + a];
          float dv = 1.f / sqrtf(rsum[r] + c1 + c2);
          dinv[u] = dv;
          sdinv[iL0 + r] = dv;
        }
      }
      __syncthreads();
      #pragma unroll
      for (int j = 0; j < 4; j++) {
        int jn = j * 16 + fr;
        float dj = sdinv[jn];
        #pragma unroll
        for (int r = 0; r < 4; r++)
          intra_s[mb * 4096 + (iL0 + r) * 64 + jn] = f2bf(ang[j][r] * sdinv[iL0 + r] * dj);
      }
      __syncthreads();
    } else {
      const int q = t - 96;
      const int c0 = (q / 96) * 16;
      const int n0 = ((q % 96) * 4 + w) * 16;
      f32x4 acc = {};
      gemm1<7>(fc0_wt + c0 * 224, 224, bigA + n0 * 224, 224, acc);
      const int node = n0 + (lane & 15), cb = c0 + (lane >> 4) * 4;
      if (cb < 200) {
        s16x4 oh;
        #pragma unroll
        for (int r = 0; r < 4; r++) {
          float v = fmaxf(acc[r] + fc0_b[cb + r], 0.f);
          oh[r] = f2bf(v);
          h_t[(cb + r) * 6144 + node] = oh[r];
        }
        *(s16x4*)(convA + node * 416 + 200 + cb) = oh;
      }
    }
  }
  grid_barrier(slots, gen, ++gctr);

  // ================= GCNII layers: adj -> conv, twice =================
  #pragma unroll 1
  for (int layer = 0; layer < 2; layer++) {
    for (int t = bx; t < 1248; t += NBLK) {  // adj
      const int ct = t / 96, mb = t - ct * 96;
      const int c0 = ct * 16, nbase = mb * 64;
      f32x4 acc = {};
      gemm1<2>(h_t + c0 * 6144 + nbase, 6144, intra_s + mb * 4096 + w * 16 * 64, 64, acc);
      const int u = nbase + w * 16 + (lane & 15), cb = c0 + (lane >> 4) * 4;
      if (cb < 200) {
        const int m = u >> 11, a = u & 2047;
        int n1, n2, p1, p2;
        if (m == 0)      { n1 = 1; p1 = 0; n2 = 2; p2 = 1; }
        else if (m == 1) { n1 = 0; p1 = 0; n2 = 2; p2 = 2; }
        else             { n1 = 0; p1 = 1; n2 = 1; p2 = 2; }
        float dv = dinv[u];
        int o1 = n1 * 2048 + a, o2 = n2 * 2048 + a;
        float w1 = cw[p1 * 2048 + a] * dv * dinv[o1];
        float w2 = cw[p2 * 2048 + a] * dv * dinv[o2];
        s16x4 o;
        #pragma unroll
        for (int r = 0; r < 4; r++) {
          int c = cb + r;
          float v = acc[r] + w1 * bf2f(h_t[c * 6144 + o1]) + w2 * bf2f(h_t[c * 6144 + o2]);
          o[r] = f2bf(v);
        }
        *(s16x4*)(convA + u * 416 + cb) = o;
      }
    }
    grid_barrier(slots, gen, ++gctr);

    const float beta = (layer == 0) ? 0.40546510810816444f : 0.22314355131420976f;
    const float ombeta = 1.f - beta;
    const short* Wt = conv_wt + layer * 86528;
    for (int t = bx; t < 1248; t += NBLK) {  // conv
      const int c0 = (t / 96) * 16;
      const int n0 = ((t % 96) * 4 + w) * 16;
      f32x4 acc = {};
      gemm1<13>(Wt + c0 * 416, 416, convA + n0 * 416, 416, acc);
      const int node = n0 + (lane & 15), cb = c0 + (lane >> 4) * 4;
      if (cb < 200) {
        s16x4 hiv = *(const s16x4*)(convA + node * 416 + cb);
        s16x4 h0v = *(const s16x4*)(convA + node * 416 + 200 + cb);
        if (layer == 0) {
          #pragma unroll
          for (int r = 0; r < 4; r++) {
            float rr = 0.9f * bf2f(hiv[r]) + 0.1f * bf2f(h0v[r]);
            float v = fmaxf(beta * acc[r] + ombeta * rr, 0.f);
            h_t[(cb + r) * 6144 + node] = f2bf(v);
          }
        } else {
          s16x4 o;
          #pragma unroll
          for (int r = 0; r < 4; r++) {
            float rr = 0.9f * bf2f(hiv[r]) + 0.1f * bf2f(h0v[r]);
            float v = fmaxf(beta * acc[r] + ombeta * rr, 0.f);
            o[r] = f2bf(v);
          }
          *(s16x4*)(tmA + node * 416 + 200 + cb) = o;
        }
      }
    }
    grid_barrier(slots, gen, ++gctr);
  }

  // ================= S7: tm =================
  for (int t = bx; t < 1248; t += NBLK) {
    const int m = t / 416, rem = t - m * 416;
    const int c0 = (rem / 32) * 16;
    const int n0 = ((rem % 32) * 4 + w) * 16;
    f32x4 acc = {};
    gemm1<13>(tm_wt + m * 86528 + c0 * 416, 416, tmA + (m * 2048 + n0) * 416, 416, acc);
    const int node = n0 + (lane & 15), cb = c0 + (lane >> 4) * 4;
    if (cb < 200) {
      s16x4 o;
      #pragma unroll
      for (int r = 0; r < 4; r++) o[r] = f2bf(fmaxf(acc[r] + tm_b[m * H + cb + r], 0.f));
      *(s16x4*)(hxb + (m * 2048 + node) * 224 + cb) = o;
    }
  }
  grid_barrier(slots, gen, ++gctr);

  // ================= S8: cross gate (3-phase) + fused final projection =================
  for (int t = bx; t < 2496; t += NBLK) {
    const int p = t / 416, rem = t - p * 416;
    const int cj = rem / 32;
    const int c0 = cj * 16;
    const int n0 = ((rem % 32) * 4 + w) * 16;
    const int im = p >> 1, jm = jm_t[p];
    const short* Wp = cross_wt + p * (3 * 208 * 224);
    const short* Bi = hxb + (im * 2048 + n0) * 224;
    const short* Bj = hxb + (jm * 2048 + n0) * 224;
    f32x4 acc = {};
    gemm1<7>(Wp + c0 * 224, 224, Bi, 224, acc);
    gemm1<7>(Wp + 208 * 224 + c0 * 224, 224, Bj, 224, acc);
    {
      const short* ap = Wp + 2 * 208 * 224 + (c0 + (lane & 15)) * 224 + (lane >> 4) * 8;
      const short* bpi = Bi + (lane & 15) * 224 + (lane >> 4) * 8;
      const short* bpj = Bj + (lane & 15) * 224 + (lane >> 4) * 8;
      #pragma unroll
      for (int tt = 0; tt < 7; tt++) {
        bf16x8 a = *(const bf16x8*)(ap + tt * 32);
        bf16x8 bi = *(const bf16x8*)(bpi + tt * 32);
        bf16x8 bj = *(const bf16x8*)(bpj + tt * 32);
        bf16x8 pr;
        #pragma unroll
        for (int e = 0; e < 8; e++) pr[e] = f2bf(bf2f(bi[e]) * bf2f(bj[e]));
        acc = __builtin_amdgcn_mfma_f32_16x16x32_bf16(a, pr, acc, 0, 0, 0);
      }
    }
    const int node = n0 + (lane & 15), cb = c0 + (lane >> 4) * 4;
    float pt[6] = {0.f, 0.f, 0.f, 0.f, 0.f, 0.f};
    if (cb < 200) {
      s16x4 ai = *(const s16x4*)(hxb + (im * 2048 + node) * 224 + cb);
      s16x4 aj = *(const s16x4*)(hxb + (jm * 2048 + node) * 224 + cb);
      const float* Wu = uniw + im * (H * 6);
      #pragma unroll
      for (int r = 0; r < 4; r++) {
        float x = acc[r] + cross_b[p * H + cb + r];
        float z = 1.f / (1.f + expf(-x));
        float o = z * bf2f(ai[r]) + (1.f - z) * bf2f(aj[r]);
        #pragma unroll
        for (int tt = 0; tt < 6; tt++) pt[tt] += o * Wu[(cb + r) * 6 + tt];
      }
    }
    #pragma unroll
    for (int tt = 0; tt < 6; tt++) {
      pt[tt] += __shfl_xor(pt[tt], 16, 64);
      pt[tt] += __shfl_xor(pt[tt], 32, 64);
    }
    if ((lane >> 4) == 0) {
      if (p == 0 && cj == 0) {
        #pragma unroll
        for (int tt = 0; tt < 6; tt++) pt[tt] += unib[tt] + unib[6 + tt] + unib[12 + tt];
      }
      #pragma unroll
      for (int tt = 0; tt < 6; tt++) atomicAdd(out + node * 6 + tt, pt[tt]);
    }
  }
}

extern "C" void kernel_launch(void* const* d_in, const int* in_sizes, int n_in,
                              void* d_out, int out_size, void* d_ws, size_t ws_size,
                              hipStream_t stream) {
  const float* xa = (const float*)d_in[0];
  const float* xv = (const float*)d_in[1];
  const float* xt = (const float*)d_in[2];
  const float* fc0_w = (const float*)d_in[3];
  const float* fc0_b = (const float*)d_in[4];
  const float* conv_w = (const float*)d_in[5];
  const float* tm_w = (const float*)d_in[6];
  const float* tm_b = (const float*)d_in[7];
  const float* cross_w = (const float*)d_in[8];
  const float* cross_b = (const float*)d_in[9];
  const float* uni_w = (const float*)d_in[10];
  const float* uni_b = (const float*)d_in[11];
  float* out = (float*)d_out;
  float* ws = (float*)d_ws;

  float* inv_norm = ws;                       // 6144
  float* dinv = ws + 6144;                    // 6144
  float* cw = ws + 12288;                     // 6144
  short* bigA = (short*)(ws + 18432);         // 6144*224 sh -> 706560
  short* convA = (short*)(ws + 706560);       // 6144*416 sh -> 1984512
  short* tmA = (short*)(ws + 1984512);        // 6144*416 sh -> 3262464
  short* hxb = (short*)(ws + 3262464);        // 6144*224 sh -> 3950592
  short* h_t = (short*)(ws + 3950592);        // 208*6144 sh -> 4589568
  short* intra_s = (short*)(ws + 4589568);    // 96*4096 sh -> 4786176
  short* fc0_wt = (short*)(ws + 4786176);     // 208*224 sh -> 4809472
  short* conv_wt = (short*)(ws + 4809472);    // 2*208*416 sh -> 4896000
  short* tm_wt = (short*)(ws + 4896000);      // 3*208*416 sh -> 5025792
  short* cross_wt = (short*)(ws + 5025792);   // 18*208*224 sh -> 5445120
  unsigned* syncv = (unsigned*)(ws + 5445120); // gen @ +0, slots @ +64 (512*4 uints)

  hipMemsetAsync(syncv, 0, (64 + NBLK * 4) * sizeof(unsigned), stream);
  mono_k<<<NBLK, 256, 0, stream>>>(xa, xv, xt, fc0_w, fc0_b, conv_w, tm_w, tm_b,
                                   cross_w, cross_b, uni_w, uni_b,
                                   fc0_wt, conv_wt, tm_wt, cross_wt, bigA, tmA, convA,
                                   hxb, h_t, intra_s, inv_norm, cw, dinv, syncv, out);
}